// Round 1
// baseline (421.654 us; speedup 1.0000x reference)
//
#include <hip/hip_runtime.h>
#include <math.h>

#define BB 8
#define CC 128
#define NN 65536
#define LL 64
#define CHK 128

typedef __attribute__((ext_vector_type(16))) float f32x16;
typedef __attribute__((ext_vector_type(8)))  short s16x8;

union V16 { int4 i; uint4 u; s16x8 s; };

__device__ __forceinline__ unsigned bf16rne(float f) {
    unsigned u = __builtin_bit_cast(unsigned, f);
    return (u + 0x7fffu + ((u >> 16) & 1u)) >> 16;
}
__device__ __forceinline__ unsigned packbf(float lo, float hi) {
    return bf16rne(lo) | (bf16rne(hi) << 16);
}
__device__ __forceinline__ unsigned oh2(int a, int b, int t) {
    return (a == t ? 0x3F80u : 0u) | (b == t ? 0x3F800000u : 0u);
}

// Raw barrier: drains LDS ops only, leaves global prefetch loads in flight
// (plain __syncthreads() emits s_waitcnt vmcnt(0) before s_barrier and would
//  kill the cross-chunk pipeline).  asm "memory" clobbers fence the compiler.
#define BAR_LGKM() do { \
    asm volatile("s_waitcnt lgkmcnt(0)" ::: "memory"); \
    __builtin_amdgcn_s_barrier(); \
    asm volatile("" ::: "memory"); \
} while (0)

// one block: (nchk*128) points of one batch; centers via MFMA (pred x onehot).
// NO global atomics: per-block partials written coalesced in fragment order.
// v2: software-pipelined global staging (prefetch next chunk across raw barriers),
//     conflict-free scalar prS layout for the S1/S2 cross-wave reduce.
__global__ __launch_bounds__(256, 2)
void k1_mfma(const float* __restrict__ pred, const int* __restrict__ label,
             float* __restrict__ gpart, float* __restrict__ gcp, float* __restrict__ gvp,
             int blk_per_b, int nchk)
{
    __shared__ __align__(16) unsigned pred_lds[CC * 64];   // 32 KB bf16 [c=128][n=128], swizzled
    __shared__ __align__(16) int lab_s[2048];              // 8 KB
    __shared__ float prS[4][256];                          // 4 KB  S1/S2 partials (conflict-free)
    __shared__ float vacc[LL];
    __shared__ unsigned cnt[LL];

    const int tid  = threadIdx.x;
    const int wv   = tid >> 6;      // wave = 32-channel tile
    const int lane = tid & 63;

    const int b   = blockIdx.x / blk_per_b;
    const int blk = blockIdx.x % blk_per_b;
    const int pts = nchk * CHK;
    const int n0b = blk * pts;

    const float* __restrict__ predb = pred + (size_t)b * CC * NN;
    const int*   __restrict__ labb  = label + (size_t)b * NN + n0b;

    const int src_c = tid & 127;    // staging row (channel)
    const int src_h = tid >> 7;     // staging half (64 pts)
    const float* __restrict__ gpbase = predb + (size_t)src_c * NN + n0b + src_h * 64;

    // ---- label loads issued FIRST (oldest in vmcnt order), then pred chunk-0
    //      prefetch: the label ds_write's vmcnt wait then leaves pred loads in flight.
    const int4* __restrict__ labv = (const int4*)labb;
    int4 lv0 = labv[tid];
    int4 lv1 = make_int4(0, 0, 0, 0);
    const bool two = (pts > 1024);
    if (two) lv1 = labv[tid + 256];

    float4 r[16];
    #pragma unroll
    for (int j = 0; j < 16; ++j) r[j] = *(const float4*)(gpbase + 4 * j);

    if (tid < LL) { vacc[tid] = 0.f; cnt[tid] = 0u; }
    *(int4*)&lab_s[4 * tid] = lv0;
    if (two) *(int4*)&lab_s[4 * (tid + 256)] = lv1;
    BAR_LGKM();

    for (int i = tid; i < pts; i += 256) atomicAdd(&cnt[lab_s[i]], 1u);

    f32x16 acc0, acc1;
    #pragma unroll
    for (int i = 0; i < 16; ++i) { acc0[i] = 0.f; acc1[i] = 0.f; }

    const int t0lab = lane & 31;
    const int khalf = lane >> 5;
    const int arow  = (wv << 5) + (lane & 31);

    for (int ch = 0; ch < nchk; ++ch) {
        // ---- convert current chunk (registers) -> packed bf16 ----
        uint4 w[8];
        #pragma unroll
        for (int i = 0; i < 8; ++i) {
            w[i].x = packbf(r[2*i].x,   r[2*i].y);
            w[i].y = packbf(r[2*i].z,   r[2*i].w);
            w[i].z = packbf(r[2*i+1].x, r[2*i+1].y);
            w[i].w = packbf(r[2*i+1].z, r[2*i+1].w);
        }
        // ---- prefetch next chunk; stays in flight across BOTH raw barriers ----
        if (ch + 1 < nchk) {
            const float* gp = gpbase + (ch + 1) * CHK;
            #pragma unroll
            for (int j = 0; j < 16; ++j) r[j] = *(const float4*)(gp + 4 * j);
        }
        // ---- stage packed tile to LDS (16B-quad swizzle q ^= c&15) ----
        #pragma unroll
        for (int i = 0; i < 8; ++i) {
            const int q  = 8 * src_h + i;
            const int qs = q ^ (src_c & 15);
            *(uint4*)&pred_lds[src_c * 64 + qs * 4] = w[i];
        }
        BAR_LGKM();   // b1 (vmcnt NOT drained)

        // ---- MFMA: A = pred[32ch x 16pts], B = onehot from label compares ----
        #pragma unroll
        for (int ks = 0; ks < 8; ++ks) {
            const int k0 = ks * 16;
            const int q  = (k0 >> 3) + khalf;
            const int qs = q ^ (arow & 15);
            V16 a; a.i = *(const int4*)&pred_lds[arow * 64 + qs * 4];
            const int lbase = ch * CHK + k0 + (khalf << 3);
            const int4 la = *(const int4*)&lab_s[lbase];
            const int4 lb = *(const int4*)&lab_s[lbase + 4];
            V16 b0, b1;
            b0.u = make_uint4(oh2(la.x,la.y,t0lab), oh2(la.z,la.w,t0lab),
                              oh2(lb.x,lb.y,t0lab), oh2(lb.z,lb.w,t0lab));
            const int t1lab = t0lab + 32;
            b1.u = make_uint4(oh2(la.x,la.y,t1lab), oh2(la.z,la.w,t1lab),
                              oh2(lb.x,lb.y,t1lab), oh2(lb.z,lb.w,t1lab));
            acc0 = __builtin_amdgcn_mfma_f32_32x32x16_bf16(a.s, b0.s, acc0, 0, 0, 0);
            acc1 = __builtin_amdgcn_mfma_f32_32x32x16_bf16(a.s, b1.s, acc1, 0, 0, 0);
        }

        // ---- S1/S2: transposed read, lane = point-pair, wave = 32-channel slice ----
        {
            const int p2 = tid & 63;
            float s1a=0.f, s2a=0.f, s1b=0.f, s2b=0.f;
            #pragma unroll
            for (int i2 = 0; i2 < 32; ++i2) {
                const int c  = (wv << 5) + i2;
                const int qs = (p2 >> 2) ^ (c & 15);
                const unsigned u = pred_lds[c*64 + qs*4 + (p2 & 3)];
                const float fa = __builtin_bit_cast(float, u << 16);
                const float fb = __builtin_bit_cast(float, u & 0xffff0000u);
                s1a += fa; s2a = fmaf(fa, fa, s2a);
                s1b += fb; s2b = fmaf(fb, fb, s2b);
            }
            const int idx = (wv << 6) | p2;   // lane stride 4B -> 2 lanes/bank, free
            prS[0][idx] = s1a; prS[1][idx] = s2a;
            prS[2][idx] = s1b; prS[3][idx] = s2b;
        }
        BAR_LGKM();   // b2 (vmcnt NOT drained)

        if (tid < 64) {
            const float s1 = prS[0][tid] + prS[0][tid+64] + prS[0][tid+128] + prS[0][tid+192];
            const float s2 = prS[1][tid] + prS[1][tid+64] + prS[1][tid+128] + prS[1][tid+192];
            const float u1 = prS[2][tid] + prS[2][tid+64] + prS[2][tid+128] + prS[2][tid+192];
            const float u2 = prS[3][tid] + prS[3][tid+64] + prS[3][tid+128] + prS[3][tid+192];
            float sqa = s2 - s1*s1*(1.0f/CC); sqa = sqa > 0.f ? sqa : 0.f;
            float sqb = u2 - u1*u1*(1.0f/CC); sqb = sqb > 0.f ? sqb : 0.f;
            const float da = sqrtf(sqa) - 0.5f, db = sqrtf(sqb) - 0.5f;
            const float va = da > 0.f ? da*da : 0.f, vb = db > 0.f ? db*db : 0.f;
            unsafeAtomicAdd(&vacc[lab_s[ch*CHK + 2*tid]], va);
            unsafeAtomicAdd(&vacc[lab_s[ch*CHK + 2*tid + 1]], vb);
        }
    }
    __syncthreads();

    // ---- flush: raw fragment order, perfectly coalesced float4 stores ----
    float* __restrict__ gp0 = gpart + (size_t)blockIdx.x * 8192 + wv*2048 + lane*4;
    #pragma unroll
    for (int j = 0; j < 4; ++j)
        *(float4*)(gp0 + j*256) = make_float4(acc0[4*j], acc0[4*j+1], acc0[4*j+2], acc0[4*j+3]);
    #pragma unroll
    for (int j = 0; j < 4; ++j)
        *(float4*)(gp0 + (j+4)*256) = make_float4(acc1[4*j], acc1[4*j+1], acc1[4*j+2], acc1[4*j+3]);

    if (tid < LL) {
        gcp[blockIdx.x*64 + tid] = (float)cnt[tid];
        gvp[blockIdx.x*64 + tid] = vacc[tid];
    }
}

// ---------------- kernel 1b: reduce partials, un-permute fragment layout ----------------
// blocks 0..255: (b, wv, jj) -> 256 gsum elements each. blocks 256..259: gcnt/gv.
// also zeroes d_out (runs strictly before k2; saves the memset dispatch).
__global__ __launch_bounds__(256)
void k1b_reduce(const float* __restrict__ gpart, const float* __restrict__ gcp,
                const float* __restrict__ gvp, float* __restrict__ gsum,
                float* __restrict__ gcnt, float* __restrict__ gv,
                float* __restrict__ out, int blk_per_b)
{
    const int kb = blockIdx.x, tid = threadIdx.x;
    if (kb == 0 && tid == 0) *out = 0.f;
    if (kb < 256) {
        const int b = kb >> 5, wvj = kb & 31, wv = wvj >> 3, jj = wvj & 7;
        const float* p = gpart + (size_t)b * blk_per_b * 8192 + wv*2048 + jj*256 + tid;
        float s = 0.f;
        for (int k = 0; k < blk_per_b; ++k) s += p[(size_t)k * 8192];
        const int lane = tid >> 2, q = tid & 3;
        const int l   = (lane & 31) + ((jj >> 2) << 5);
        const int r2  = (jj & 3)*4 + q;
        const int chn = (wv << 5) + (r2 & 3) + ((r2 >> 2) << 3) + ((lane >> 5) << 2);
        gsum[b*8192 + l*128 + chn] = s;
    } else {
        const int idx = (kb - 256)*256 + tid;     // 0..1023
        const int which = idx >> 9;               // 0: gcnt, 1: gv
        const int o = idx & 511;                  // b*64 + l
        const int b = o >> 6, l = o & 63;
        const float* p = (which ? gvp : gcp) + (size_t)b * blk_per_b * 64 + l;
        float s = 0.f;
        for (int k = 0; k < blk_per_b; ++k) s += p[k*64];
        if (which) gv[o] = s; else gcnt[o] = s;
    }
}

// ---------------- kernel 2: finalize (tiny) ----------------
#define CEN_STRIDE 132

__global__ __launch_bounds__(256)
void k2_finalize(const float* __restrict__ gsum, const float* __restrict__ gcnt,
                 const float* __restrict__ gv, float* __restrict__ out)
{
    __shared__ float cen[LL * CEN_STRIDE];
    __shared__ float invc[LL];
    __shared__ float red[256];

    const int tid   = threadIdx.x;
    const int b     = blockIdx.x >> 3;
    const int strip = blockIdx.x & 7;

    if (tid < LL) invc[tid] = 1.0f / gcnt[b * LL + tid];
    __syncthreads();

    const float* __restrict__ gs = gsum + (size_t)b * LL * CC;
    for (int i = tid; i < LL * CC; i += 256) {
        const int l = i >> 7, c = i & 127;
        cen[l * CEN_STRIDE + c] = gs[i] * invc[l];
    }
    __syncthreads();

    const int c  = strip * 16 + (tid >> 4);
    const int d0 = (tid & 15) * 8;

    float areg[LL];
    #pragma unroll
    for (int l = 0; l < LL; ++l) areg[l] = cen[l * CEN_STRIDE + c];

    float sqd[8] = {0.f, 0.f, 0.f, 0.f, 0.f, 0.f, 0.f, 0.f};
    #pragma unroll
    for (int l = 0; l < LL; ++l) {
        const float4 b0 = *(const float4*)&cen[l * CEN_STRIDE + d0];
        const float4 b1 = *(const float4*)&cen[l * CEN_STRIDE + d0 + 4];
        const float a = areg[l];
        float t;
        t = a - b0.x; sqd[0] += t * t;
        t = a - b0.y; sqd[1] += t * t;
        t = a - b0.z; sqd[2] += t * t;
        t = a - b0.w; sqd[3] += t * t;
        t = a - b1.x; sqd[4] += t * t;
        t = a - b1.y; sqd[5] += t * t;
        t = a - b1.z; sqd[6] += t * t;
        t = a - b1.w; sqd[7] += t * t;
    }

    float hsum = 0.f;
    #pragma unroll
    for (int j = 0; j < 8; ++j) {
        const float dist = sqd[j] > 0.f ? sqrtf(sqd[j]) : 0.f;
        float h = 3.0f - dist;
        h = h > 0.f ? h : 0.f;
        hsum += h * h;
    }
    float my = hsum * (1.0f / 8064.0f);

    if (strip == 0) {
        if (tid < CC) {
            float s = 0.f;
            #pragma unroll
            for (int l = 0; l < LL; ++l) {
                const float v = cen[l * CEN_STRIDE + tid];
                s += v * v;
            }
            my += 0.001f * sqrtf(s) * (1.0f / LL);
        }
        if (tid < LL) {
            my += gv[b * LL + tid] * invc[tid] * (1.0f / LL);
        }
    }

    red[tid] = my;
    __syncthreads();
    for (int s = 128; s > 0; s >>= 1) {
        if (tid < s) red[tid] += red[tid + s];
        __syncthreads();
    }
    if (tid == 0) unsafeAtomicAdd(out, red[0]);
}

extern "C" void kernel_launch(void* const* d_in, const int* in_sizes, int n_in,
                              void* d_out, int out_size, void* d_ws, size_t ws_size,
                              hipStream_t stream) {
    (void)in_sizes; (void)n_in; (void)out_size;
    const float* pred  = (const float*)d_in[0];
    const int*   label = (const int*)d_in[1];
    float* out = (float*)d_out;

    // pick partial-buffer width by available workspace
    const size_t need64 = ((size_t)512*8192 + (size_t)512*128 + 65536 + 1024) * sizeof(float);
    const int blk_per_b = (ws_size >= need64) ? 64 : 32;
    const int nchk      = (NN / CHK) / blk_per_b;      // 8 or 16
    const int nblk      = BB * blk_per_b;              // 512 or 256

    float* gpart = (float*)d_ws;                       // [nblk][8192]
    float* gcp   = gpart + (size_t)nblk * 8192;        // [nblk][64]
    float* gvp   = gcp + (size_t)nblk * 64;            // [nblk][64]
    float* gsum  = gvp + (size_t)nblk * 64;            // [B][L][C]
    float* gcnt  = gsum + BB * LL * CC;                // [B][L]
    float* gv    = gcnt + BB * LL;                     // [B][L]

    k1_mfma<<<nblk, 256, 0, stream>>>(pred, label, gpart, gcp, gvp, blk_per_b, nchk);
    k1b_reduce<<<260, 256, 0, stream>>>(gpart, gcp, gvp, gsum, gcnt, gv, out, blk_per_b);
    k2_finalize<<<BB * 8, 256, 0, stream>>>(gsum, gcnt, gv, out);
}

// Round 2
// 419.126 us; speedup vs baseline: 1.0060x; 1.0060x over previous
//
#include <hip/hip_runtime.h>
#include <math.h>

#define BB 8
#define CC 128
#define NN 65536
#define LL 64
#define CHK 128

typedef __attribute__((ext_vector_type(16))) float f32x16;
typedef __attribute__((ext_vector_type(8)))  short s16x8;

union V16 { int4 i; uint4 u; s16x8 s; };

__device__ __forceinline__ unsigned bf16rne(float f) {
    unsigned u = __builtin_bit_cast(unsigned, f);
    return (u + 0x7fffu + ((u >> 16) & 1u)) >> 16;
}
__device__ __forceinline__ unsigned packbf(float lo, float hi) {
    return bf16rne(lo) | (bf16rne(hi) << 16);
}
__device__ __forceinline__ unsigned oh2(int a, int b, int t) {
    return (a == t ? 0x3F80u : 0u) | (b == t ? 0x3F800000u : 0u);
}

// Raw barrier: drains LDS ops only, leaves global prefetch loads in flight.
#define BAR_LGKM() do { \
    asm volatile("s_waitcnt lgkmcnt(0)" ::: "memory"); \
    __builtin_amdgcn_s_barrier(); \
    asm volatile("" ::: "memory"); \
} while (0)

// one block: (nchk*128) points of one batch; centers via MFMA (pred x onehot).
// v3: POINT-MAJOR staging reads. Previous layout made every load instruction
// touch 64 scattered 64B lines (lane i -> row i, 256KB apart). Now lane group
// (t&31) spans a full 512B chunk-row: each global_load_dwordx4 covers 2 rows
// as 2x512B contiguous segments -> DRAM burst efficiency like the fill kernels.
// LDS tile layout (u32 u <-> points 2u,2u+1, quad swizzle q^=c&15) unchanged.
__global__ __launch_bounds__(256, 2)
void k1_mfma(const float* __restrict__ pred, const int* __restrict__ label,
             float* __restrict__ gpart, float* __restrict__ gcp, float* __restrict__ gvp,
             int blk_per_b, int nchk)
{
    __shared__ __align__(16) unsigned pred_lds[CC * 64];   // 32 KB bf16 [c=128][n=128], swizzled
    __shared__ __align__(16) int lab_s[2048];              // 8 KB
    __shared__ float prS[4][256];                          // 4 KB  S1/S2 partials (conflict-free)
    __shared__ float vacc[LL];
    __shared__ unsigned cnt[LL];

    const int tid  = threadIdx.x;
    const int wv   = tid >> 6;      // wave = 32-channel tile
    const int lane = tid & 63;

    const int b   = blockIdx.x / blk_per_b;
    const int blk = blockIdx.x % blk_per_b;
    const int pts = nchk * CHK;
    const int n0b = blk * pts;

    const float* __restrict__ predb = pred + (size_t)b * CC * NN;
    const int*   __restrict__ labb  = label + (size_t)b * NN + n0b;

    // point-major reader geometry: row base rr, float-col cc4
    const int rr  = tid >> 5;           // 0..7
    const int cc4 = (tid & 31) * 4;     // 0..124
    const float* __restrict__ gpbase = predb + (size_t)rr * NN + n0b + cc4;

    // ---- label loads issued FIRST (oldest in vmcnt order), then pred chunk-0
    const int4* __restrict__ labv = (const int4*)labb;
    int4 lv0 = labv[tid];
    int4 lv1 = make_int4(0, 0, 0, 0);
    const bool two = (pts > 1024);
    if (two) lv1 = labv[tid + 256];

    float4 r[16];
    #pragma unroll
    for (int j = 0; j < 16; ++j) r[j] = *(const float4*)(gpbase + (size_t)(8 * j) * NN);

    if (tid < LL) { vacc[tid] = 0.f; cnt[tid] = 0u; }
    *(int4*)&lab_s[4 * tid] = lv0;
    if (two) *(int4*)&lab_s[4 * (tid + 256)] = lv1;
    BAR_LGKM();

    for (int i = tid; i < pts; i += 256) atomicAdd(&cnt[lab_s[i]], 1u);

    f32x16 acc0, acc1;
    #pragma unroll
    for (int i = 0; i < 16; ++i) { acc0[i] = 0.f; acc1[i] = 0.f; }

    const int t0lab = lane & 31;
    const int khalf = lane >> 5;
    const int arow  = (wv << 5) + (lane & 31);

    // precomputed LDS write geometry (per j: row c = rr + 8j)
    const int qbase = (tid & 31) >> 1;        // quad before swizzle
    const int wofs  = (tid & 1) << 1;         // u32 offset inside quad (0 or 2)

    for (int ch = 0; ch < nchk; ++ch) {
        // ---- convert current chunk (registers) -> packed bf16 ----
        uint2 w[16];
        #pragma unroll
        for (int j = 0; j < 16; ++j) {
            w[j].x = packbf(r[j].x, r[j].y);
            w[j].y = packbf(r[j].z, r[j].w);
        }
        // ---- prefetch next chunk; stays in flight across BOTH raw barriers ----
        if (ch + 1 < nchk) {
            const float* gp = gpbase + (ch + 1) * CHK;
            #pragma unroll
            for (int j = 0; j < 16; ++j) r[j] = *(const float4*)(gp + (size_t)(8 * j) * NN);
        }
        // ---- stage packed tile to LDS (16B-quad swizzle q ^= c&15) ----
        #pragma unroll
        for (int j = 0; j < 16; ++j) {
            const int c  = rr + 8 * j;
            const int qs = qbase ^ (c & 15);
            *(uint2*)&pred_lds[c * 64 + qs * 4 + wofs] = w[j];
        }
        BAR_LGKM();   // b1 (vmcnt NOT drained)

        // ---- MFMA: A = pred[32ch x 16pts], B = onehot from label compares ----
        #pragma unroll
        for (int ks = 0; ks < 8; ++ks) {
            const int k0 = ks * 16;
            const int q  = (k0 >> 3) + khalf;
            const int qs = q ^ (arow & 15);
            V16 a; a.i = *(const int4*)&pred_lds[arow * 64 + qs * 4];
            const int lbase = ch * CHK + k0 + (khalf << 3);
            const int4 la = *(const int4*)&lab_s[lbase];
            const int4 lb = *(const int4*)&lab_s[lbase + 4];
            V16 b0, b1;
            b0.u = make_uint4(oh2(la.x,la.y,t0lab), oh2(la.z,la.w,t0lab),
                              oh2(lb.x,lb.y,t0lab), oh2(lb.z,lb.w,t0lab));
            const int t1lab = t0lab + 32;
            b1.u = make_uint4(oh2(la.x,la.y,t1lab), oh2(la.z,la.w,t1lab),
                              oh2(lb.x,lb.y,t1lab), oh2(lb.z,lb.w,t1lab));
            acc0 = __builtin_amdgcn_mfma_f32_32x32x16_bf16(a.s, b0.s, acc0, 0, 0, 0);
            acc1 = __builtin_amdgcn_mfma_f32_32x32x16_bf16(a.s, b1.s, acc1, 0, 0, 0);
        }

        // ---- S1/S2: transposed read, lane = point-pair, wave = 32-channel slice ----
        {
            const int p2 = tid & 63;
            float s1a=0.f, s2a=0.f, s1b=0.f, s2b=0.f;
            #pragma unroll
            for (int i2 = 0; i2 < 32; ++i2) {
                const int c  = (wv << 5) + i2;
                const int qs = (p2 >> 2) ^ (c & 15);
                const unsigned u = pred_lds[c*64 + qs*4 + (p2 & 3)];
                const float fa = __builtin_bit_cast(float, u << 16);
                const float fb = __builtin_bit_cast(float, u & 0xffff0000u);
                s1a += fa; s2a = fmaf(fa, fa, s2a);
                s1b += fb; s2b = fmaf(fb, fb, s2b);
            }
            const int idx = (wv << 6) | p2;   // lane stride 4B -> 2 lanes/bank, free
            prS[0][idx] = s1a; prS[1][idx] = s2a;
            prS[2][idx] = s1b; prS[3][idx] = s2b;
        }
        BAR_LGKM();   // b2 (vmcnt NOT drained)

        if (tid < 64) {
            const float s1 = prS[0][tid] + prS[0][tid+64] + prS[0][tid+128] + prS[0][tid+192];
            const float s2 = prS[1][tid] + prS[1][tid+64] + prS[1][tid+128] + prS[1][tid+192];
            const float u1 = prS[2][tid] + prS[2][tid+64] + prS[2][tid+128] + prS[2][tid+192];
            const float u2 = prS[3][tid] + prS[3][tid+64] + prS[3][tid+128] + prS[3][tid+192];
            float sqa = s2 - s1*s1*(1.0f/CC); sqa = sqa > 0.f ? sqa : 0.f;
            float sqb = u2 - u1*u1*(1.0f/CC); sqb = sqb > 0.f ? sqb : 0.f;
            const float da = sqrtf(sqa) - 0.5f, db = sqrtf(sqb) - 0.5f;
            const float va = da > 0.f ? da*da : 0.f, vb = db > 0.f ? db*db : 0.f;
            unsafeAtomicAdd(&vacc[lab_s[ch*CHK + 2*tid]], va);
            unsafeAtomicAdd(&vacc[lab_s[ch*CHK + 2*tid + 1]], vb);
        }
    }
    __syncthreads();

    // ---- flush: raw fragment order, perfectly coalesced float4 stores ----
    float* __restrict__ gp0 = gpart + (size_t)blockIdx.x * 8192 + wv*2048 + lane*4;
    #pragma unroll
    for (int j = 0; j < 4; ++j)
        *(float4*)(gp0 + j*256) = make_float4(acc0[4*j], acc0[4*j+1], acc0[4*j+2], acc0[4*j+3]);
    #pragma unroll
    for (int j = 0; j < 4; ++j)
        *(float4*)(gp0 + (j+4)*256) = make_float4(acc1[4*j], acc1[4*j+1], acc1[4*j+2], acc1[4*j+3]);

    if (tid < LL) {
        gcp[blockIdx.x*64 + tid] = (float)cnt[tid];
        gvp[blockIdx.x*64 + tid] = vacc[tid];
    }
}

// ---------------- kernel 1b: reduce partials, un-permute fragment layout ----------------
// blocks 0..255: (b, wv, jj) -> 256 gsum elements each. blocks 256..259: gcnt/gv.
// also zeroes d_out (runs strictly before k2; saves the memset dispatch).
__global__ __launch_bounds__(256)
void k1b_reduce(const float* __restrict__ gpart, const float* __restrict__ gcp,
                const float* __restrict__ gvp, float* __restrict__ gsum,
                float* __restrict__ gcnt, float* __restrict__ gv,
                float* __restrict__ out, int blk_per_b)
{
    const int kb = blockIdx.x, tid = threadIdx.x;
    if (kb == 0 && tid == 0) *out = 0.f;
    if (kb < 256) {
        const int b = kb >> 5, wvj = kb & 31, wv = wvj >> 3, jj = wvj & 7;
        const float* p = gpart + (size_t)b * blk_per_b * 8192 + wv*2048 + jj*256 + tid;
        float s = 0.f;
        for (int k = 0; k < blk_per_b; ++k) s += p[(size_t)k * 8192];
        const int lane = tid >> 2, q = tid & 3;
        const int l   = (lane & 31) + ((jj >> 2) << 5);
        const int r2  = (jj & 3)*4 + q;
        const int chn = (wv << 5) + (r2 & 3) + ((r2 >> 2) << 3) + ((lane >> 5) << 2);
        gsum[b*8192 + l*128 + chn] = s;
    } else {
        const int idx = (kb - 256)*256 + tid;     // 0..1023
        const int which = idx >> 9;               // 0: gcnt, 1: gv
        const int o = idx & 511;                  // b*64 + l
        const int b = o >> 6, l = o & 63;
        const float* p = (which ? gvp : gcp) + (size_t)b * blk_per_b * 64 + l;
        float s = 0.f;
        for (int k = 0; k < blk_per_b; ++k) s += p[k*64];
        if (which) gv[o] = s; else gcnt[o] = s;
    }
}

// ---------------- kernel 2: finalize (tiny) ----------------
#define CEN_STRIDE 132

__global__ __launch_bounds__(256)
void k2_finalize(const float* __restrict__ gsum, const float* __restrict__ gcnt,
                 const float* __restrict__ gv, float* __restrict__ out)
{
    __shared__ float cen[LL * CEN_STRIDE];
    __shared__ float invc[LL];
    __shared__ float red[256];

    const int tid   = threadIdx.x;
    const int b     = blockIdx.x >> 3;
    const int strip = blockIdx.x & 7;

    if (tid < LL) invc[tid] = 1.0f / gcnt[b * LL + tid];
    __syncthreads();

    const float* __restrict__ gs = gsum + (size_t)b * LL * CC;
    for (int i = tid; i < LL * CC; i += 256) {
        const int l = i >> 7, c = i & 127;
        cen[l * CEN_STRIDE + c] = gs[i] * invc[l];
    }
    __syncthreads();

    const int c  = strip * 16 + (tid >> 4);
    const int d0 = (tid & 15) * 8;

    float areg[LL];
    #pragma unroll
    for (int l = 0; l < LL; ++l) areg[l] = cen[l * CEN_STRIDE + c];

    float sqd[8] = {0.f, 0.f, 0.f, 0.f, 0.f, 0.f, 0.f, 0.f};
    #pragma unroll
    for (int l = 0; l < LL; ++l) {
        const float4 b0 = *(const float4*)&cen[l * CEN_STRIDE + d0];
        const float4 b1 = *(const float4*)&cen[l * CEN_STRIDE + d0 + 4];
        const float a = areg[l];
        float t;
        t = a - b0.x; sqd[0] += t * t;
        t = a - b0.y; sqd[1] += t * t;
        t = a - b0.z; sqd[2] += t * t;
        t = a - b0.w; sqd[3] += t * t;
        t = a - b1.x; sqd[4] += t * t;
        t = a - b1.y; sqd[5] += t * t;
        t = a - b1.z; sqd[6] += t * t;
        t = a - b1.w; sqd[7] += t * t;
    }

    float hsum = 0.f;
    #pragma unroll
    for (int j = 0; j < 8; ++j) {
        const float dist = sqd[j] > 0.f ? sqrtf(sqd[j]) : 0.f;
        float h = 3.0f - dist;
        h = h > 0.f ? h : 0.f;
        hsum += h * h;
    }
    float my = hsum * (1.0f / 8064.0f);

    if (strip == 0) {
        if (tid < CC) {
            float s = 0.f;
            #pragma unroll
            for (int l = 0; l < LL; ++l) {
                const float v = cen[l * CEN_STRIDE + tid];
                s += v * v;
            }
            my += 0.001f * sqrtf(s) * (1.0f / LL);
        }
        if (tid < LL) {
            my += gv[b * LL + tid] * invc[tid] * (1.0f / LL);
        }
    }

    red[tid] = my;
    __syncthreads();
    for (int s = 128; s > 0; s >>= 1) {
        if (tid < s) red[tid] += red[tid + s];
        __syncthreads();
    }
    if (tid == 0) unsafeAtomicAdd(out, red[0]);
}

extern "C" void kernel_launch(void* const* d_in, const int* in_sizes, int n_in,
                              void* d_out, int out_size, void* d_ws, size_t ws_size,
                              hipStream_t stream) {
    (void)in_sizes; (void)n_in; (void)out_size;
    const float* pred  = (const float*)d_in[0];
    const int*   label = (const int*)d_in[1];
    float* out = (float*)d_out;

    // pick partial-buffer width by available workspace
    const size_t need64 = ((size_t)512*8192 + (size_t)512*128 + 65536 + 1024) * sizeof(float);
    const int blk_per_b = (ws_size >= need64) ? 64 : 32;
    const int nchk      = (NN / CHK) / blk_per_b;      // 8 or 16
    const int nblk      = BB * blk_per_b;              // 512 or 256

    float* gpart = (float*)d_ws;                       // [nblk][8192]
    float* gcp   = gpart + (size_t)nblk * 8192;        // [nblk][64]
    float* gvp   = gcp + (size_t)nblk * 64;            // [nblk][64]
    float* gsum  = gvp + (size_t)nblk * 64;            // [B][L][C]
    float* gcnt  = gsum + BB * LL * CC;                // [B][L]
    float* gv    = gcnt + BB * LL;                     // [B][L]

    k1_mfma<<<nblk, 256, 0, stream>>>(pred, label, gpart, gcp, gvp, blk_per_b, nchk);
    k1b_reduce<<<260, 256, 0, stream>>>(gpart, gcp, gvp, gsum, gcnt, gv, out, blk_per_b);
    k2_finalize<<<BB * 8, 256, 0, stream>>>(gsum, gcnt, gv, out);
}